// Round 12
// baseline (22.416 us; speedup 1.0000x reference)
//
#include <hip/hip_runtime.h>
#include <stdint.h>

#define HW 65536
#define WIMG 256
#define TOPK 100
#define CAP2 2048            // per-group fallback capacity
#define CAPC 64              // per-(group,chunk) slab capacity (E=20.5, 9.6 sigma)
#define NCHUNK 8             // filter blocks per group
#define NGROUP 128           // 64 batches x 2 heatmaps
#define FTHR 512             // filter block size (1024 blocks x 8 waves = full machine)

// Monotone float->uint key (handles negatives; data is [0,1)).
__device__ __forceinline__ uint32_t fkey(float v) {
    uint32_t b = __float_as_uint(v);
    return b ^ ((b & 0x80000000u) ? 0xFFFFFFFFu : 0x80000000u);
}

// ws byte layout (fast path):
//   [0, 524288)         u64 cand[1024][64]
//   [524288, 528384)    u32 chunkcnt[1024]
//   [528384, 528896)    f32 partials[128]  (loss,mask per batch)
//   [528896, 528900)    u32 done counter
#define CAND_OFF  0
#define CNT_OFF   524288
#define PART_OFF  528384
#define DONE_OFF  528896
#define WS_FAST_BYTES 528900

// top-100 of 65536 uniforms ~ 0.99847; 0.9975 gives E=164/group, E=20.5/chunk
// (bisection fallback preserves correctness for arbitrary data)
#define FILT_THR 0.9975f

#define AGENT __HIP_MEMORY_SCOPE_AGENT

// ---------------- kernel A: filter (1024 blocks x 512 thr) ----------------
__global__ __launch_bounds__(FTHR) void filter_kernel(
    const float* __restrict__ hm_p, const float* __restrict__ hm_t,
    unsigned long long* __restrict__ cand, uint32_t* __restrict__ chunkcnt,
    uint32_t* __restrict__ done_cnt)
{
    __shared__ unsigned long long lbuf[CAPC];
    __shared__ uint32_t lcnt;

    const int blk   = blockIdx.x;        // 0..1023
    const int group = blk >> 3;
    const int chunk = blk & (NCHUNK - 1);
    const int which = group & 1;
    const int b     = group >> 1;
    const float* src = (which ? hm_t : hm_p) + (size_t)b * HW + chunk * (HW / NCHUNK);
    const float4* src4 = (const float4*)src;
    const int base0 = chunk * (HW / NCHUNK);

    if (blk == 0 && threadIdx.x == 0) *done_cnt = 0;    // boundary orders before K2

    if (threadIdx.x == 0) lcnt = 0;
    __syncthreads();

    #pragma unroll
    for (int t = 0; t < HW / NCHUNK / 4 / FTHR; ++t) {   // 4 iters
        const int i = threadIdx.x + t * FTHR;
        float4 v = src4[i];
        const int base = base0 + i * 4;
        float f[4] = {v.x, v.y, v.z, v.w};
        #pragma unroll
        for (int e = 0; e < 4; ++e) {
            if (f[e] > FILT_THR) {                      // float cmp; key only on hit
                uint32_t pos = atomicAdd(&lcnt, 1u);    // LDS atomic: intra-CU
                if (pos < CAPC)
                    lbuf[pos] = ((unsigned long long)fkey(f[e]) << 16) |
                                (unsigned long long)(65535 - (base + e));
            }
        }
    }
    __syncthreads();
    const uint32_t c = lcnt;
    if (threadIdx.x == 0) chunkcnt[blk] = c;            // plain store
    unsigned long long* gc = cand + (size_t)blk * CAPC;
    if (threadIdx.x < min(c, (uint32_t)CAPC))
        gc[threadIdx.x] = lbuf[threadIdx.x];            // c <= 64 < 512
}

// ---- kernel B: per-batch gather + rank-select (both groups) + loss + final --
__device__ __forceinline__ float gwd(float px, float py, float pw, float ph, float pr,
                                     float tx, float ty, float tw, float th, float trg)
{
    pw = fminf(fmaxf(pw, 1e-7f), 1e7f);  ph = fminf(fmaxf(ph, 1e-7f), 1e7f);
    tw = fminf(fmaxf(tw, 1e-7f), 1e7f);  th = fminf(fmaxf(th, 1e-7f), 1e7f);
    const float d2r = 0.017453292519943295f;
    float rp = pr * d2r, rt = trg * d2r;
    float cp = cosf(rp), sp = sinf(rp);
    float ct = cosf(rt), st = sinf(rt);
    float ap = 0.5f * pw, bp = 0.5f * ph;
    float at = 0.5f * tw, bt = 0.5f * th;
    float ap2 = ap * ap, bp2 = bp * bp, at2 = at * at, bt2 = bt * bt;
    float p00 = ap2 * cp * cp + bp2 * sp * sp;
    float p11 = ap2 * sp * sp + bp2 * cp * cp;
    float p01 = (ap2 - bp2) * cp * sp;
    float t00 = at2 * ct * ct + bt2 * st * st;
    float t11 = at2 * st * st + bt2 * ct * ct;
    float t01 = (at2 - bt2) * ct * st;
    float dx = px - tx, dy = py - ty;
    float xyd = dx * dx + dy * dy;
    float whr = ap2 + bp2 + at2 + bt2;
    float trc = p00 * t00 + 2.f * p01 * t01 + p11 * t11;
    float dets = (ap * bp) * (at * bt);
    whr -= 2.f * sqrtf(fmaxf(trc + 2.f * dets, 0.f));
    float dist = fmaxf(xyd + whr, 0.f);
    float d = log1pf(dist);
    return 1.f - 1.f / (1.f + d);
}

__global__ __launch_bounds__(256) void rank_loss_kernel(
    const float* __restrict__ hm_p, const float* __restrict__ hm_t,
    const float* __restrict__ ab_p,  const float* __restrict__ ang_p,
    const float* __restrict__ ab_t,  const float* __restrict__ ang_t,
    const int*   __restrict__ ind,   const int*   __restrict__ reg_mask,
    const unsigned long long* __restrict__ cand, const uint32_t* __restrict__ chunkcnt,
    float* __restrict__ partials, uint32_t* __restrict__ done_cnt,
    float* __restrict__ out)
{
    __shared__ unsigned long long s[2][CAP2];    // 32 KB
    __shared__ float xs[2][TOPK], ys[2][TOPK];
    __shared__ uint32_t s_cs[2][NCHUNK], s_off[2][NCHUNK], s_tot[2], s_ok[2];
    __shared__ uint32_t s_cnt, s_kthr, s_klo, s_khi, s_old;
    __shared__ float sl[4], sm[4];

    const int tid = threadIdx.x;
    const int b   = blockIdx.x;                  // 0..63

    // counts + offsets for both groups
    if (tid < 2 * NCHUNK) {
        const int h = tid >> 3, k = tid & 7;
        s_cs[h][k] = chunkcnt[(2 * b + h) * NCHUNK + k];
    }
    __syncthreads();
    if (tid < 2) {
        uint32_t off = 0; int ok = 1;
        #pragma unroll
        for (int k = 0; k < NCHUNK; ++k) {
            s_off[tid][k] = off;
            if (s_cs[tid][k] > CAPC) ok = 0;
            off += s_cs[tid][k];
        }
        s_tot[tid] = off;
        s_ok[tid]  = (ok && off >= TOPK && off <= CAP2) ? 1u : 0u;
    }
    // default pad (matches prior c<100 semantics: idx=0xFFFF -> x=y=255)
    if (tid < TOPK) {
        xs[0][tid] = 255.f; ys[0][tid] = 255.f;
        xs[1][tid] = 255.f; ys[1][tid] = 255.f;
    }
    __syncthreads();

    // gather both groups: 16 slabs x 16 lanes
    for (int h = 0; h < 2; ++h) {
        if (s_ok[h]) {
            const int k  = tid >> 5;             // 0..7
            const int i0 = tid & 31;
            const unsigned long long* gc =
                cand + (size_t)((2 * b + h) * NCHUNK + k) * CAPC;
            const uint32_t ck = s_cs[h][k], ofk = s_off[h][k];
            for (uint32_t i = i0; i < ck; i += 32) s[h][ofk + i] = gc[i];
        }
    }
    __syncthreads();

    // fallback bisection per group (rare; uniform block branch)
    for (int h = 0; h < 2; ++h) {
        if (!s_ok[h]) {
            const float* src = (h ? hm_t : hm_p) + (size_t)b * HW;
            const float4* src4 = (const float4*)src;
            if (tid == 0) { s_kthr = fkey(0.99f); s_klo = 0u; s_khi = 0xFFFFFFFFu; }
            __syncthreads();
            for (int it = 0; it < 48; ++it) {
                if (tid == 0) s_cnt = 0;
                __syncthreads();
                const uint32_t kthr = s_kthr;
                for (int t = 0; t < HW / 4 / 256; ++t) {
                    float4 v = src4[tid + t * 256];
                    const int base = (tid + t * 256) * 4;
                    float f[4] = {v.x, v.y, v.z, v.w};
                    #pragma unroll
                    for (int e = 0; e < 4; ++e) {
                        uint32_t uk = fkey(f[e]);
                        if (uk > kthr) {
                            uint32_t pos = atomicAdd(&s_cnt, 1u);
                            if (pos < CAP2)
                                s[h][pos] = ((unsigned long long)uk << 16) |
                                            (unsigned long long)(65535 - (base + e));
                        }
                    }
                }
                __syncthreads();
                const uint32_t cc = s_cnt;
                if (cc >= TOPK && cc <= CAP2) break;
                if (tid == 0) {
                    if (cc < TOPK) { s_khi = s_kthr; s_kthr = s_klo + ((s_kthr - s_klo) >> 1); }
                    else           { s_klo = s_kthr; s_kthr = s_kthr + ((s_khi - s_kthr) >> 1); }
                }
                __syncthreads();
            }
            if (tid == 0) s_tot[h] = min(s_cnt, (uint32_t)CAP2);
            __syncthreads();
        }
    }
    __syncthreads();

    // rank-select both groups into LDS xs/ys
    for (int h = 0; h < 2; ++h) {
        const int c = (int)s_tot[h];
        for (int i = tid; i < c; i += 256) {
            const unsigned long long mine = s[h][i];
            int rank = 0;
            for (int j = 0; j < c; ++j)
                rank += (s[h][j] > mine) ? 1 : 0;
            if (rank < TOPK) {
                uint32_t idx = 65535u - (uint32_t)(mine & 0xFFFFull);
                xs[h][rank] = (float)(idx & (WIMG - 1));
                ys[h][rank] = (float)(idx >> 8);
            }
        }
    }
    __syncthreads();

    // loss for batch b
    const int j = tid;
    float loss = 0.f, msum = 0.f;
    if (j < TOPK) {
        const int i = b * TOPK + j;
        float m = (float)reg_mask[i];
        msum = m;
        int id = ind[i];
        float ab0 = ab_p[(size_t)(b * 2 + 0) * HW + id];
        float ab1 = ab_p[(size_t)(b * 2 + 1) * HW + id];
        float ang = ang_p[(size_t)b * HW + id];
        float px = xs[0][j] * m, py = ys[0][j] * m;
        float pw = 2.f * ab0 * m, ph = 2.f * ab1 * m;
        float pr = (ang - 90.f) * m;
        float tx = xs[1][j] * m, ty = ys[1][j] * m;
        float tw = 2.f * ab_t[b * 200 + j * 2 + 0] * m;
        float th = 2.f * ab_t[b * 200 + j * 2 + 1] * m;
        float trg = (ang_t[i] - 90.f) * m;
        loss = gwd(px, py, pw, ph, pr, tx, ty, tw, th, trg);
    }
    #pragma unroll
    for (int off = 32; off > 0; off >>= 1) {
        loss += __shfl_down(loss, off);
        msum += __shfl_down(msum, off);
    }
    const int w = tid >> 6;
    if ((tid & 63) == 0) { sl[w] = loss; sm[w] = msum; }
    __syncthreads();
    if (tid == 0) {
        __hip_atomic_store(&partials[b * 2],     sl[0] + sl[1] + sl[2] + sl[3],
                           __ATOMIC_RELEASE, AGENT);
        __hip_atomic_store(&partials[b * 2 + 1], sm[0] + sm[1] + sm[2] + sm[3],
                           __ATOMIC_RELEASE, AGENT);
        s_old = __hip_atomic_fetch_add(done_cnt, 1u, __ATOMIC_ACQ_REL, AGENT);
    }
    __syncthreads();
    if (s_old == 63u && tid < 64) {
        float L = __hip_atomic_load(&partials[2 * tid],     __ATOMIC_ACQUIRE, AGENT);
        float M = __hip_atomic_load(&partials[2 * tid + 1], __ATOMIC_ACQUIRE, AGENT);
        #pragma unroll
        for (int off = 32; off > 0; off >>= 1) {
            L += __shfl_down(L, off);
            M += __shfl_down(M, off);
        }
        if (tid == 0) out[0] = L / (M + 1e-8f);
    }
}

// ---------------- slow path (tiny ws): R8 structure ----------------
#define XY_OFF2    0
#define PART_OFF2  102400
#define FDONE_OFF2 102912

__global__ __launch_bounds__(1024) void topk_sort_kernel(
    const float* __restrict__ hm_p, const float* __restrict__ hm_t,
    float* __restrict__ xy, uint32_t* __restrict__ fdone)
{
    __shared__ unsigned long long s[CAP2];
    __shared__ uint32_t lcnt, s_kthr, s_klo, s_khi;

    const int tid   = threadIdx.x;
    const int group = blockIdx.x;
    const int which = group & 1;
    const int b     = group >> 1;

    if (group == 0 && tid == 0) *fdone = 0u;

    const float* src = (which ? hm_t : hm_p) + (size_t)b * HW;
    const float4* src4 = (const float4*)src;

    if (tid == 0) lcnt = 0;
    __syncthreads();
    #pragma unroll 4
    for (int t = 0; t < HW / 4 / 1024; ++t) {
        const int i = tid + t * 1024;
        float4 v = src4[i];
        const int base = i * 4;
        float f[4] = {v.x, v.y, v.z, v.w};
        #pragma unroll
        for (int e = 0; e < 4; ++e) {
            if (f[e] > FILT_THR) {
                uint32_t pos = atomicAdd(&lcnt, 1u);
                if (pos < CAP2)
                    s[pos] = ((unsigned long long)fkey(f[e]) << 16) |
                             (unsigned long long)(65535 - (base + e));
            }
        }
    }
    __syncthreads();
    uint32_t c = lcnt;

    if (c < TOPK || c > CAP2) {
        if (tid == 0) { s_kthr = fkey(0.99f); s_klo = 0u; s_khi = 0xFFFFFFFFu; }
        __syncthreads();
        for (int it = 0; it < 48; ++it) {
            if (tid == 0) lcnt = 0;
            __syncthreads();
            const uint32_t kthr = s_kthr;
            for (int t = 0; t < HW / 4 / 1024; ++t) {
                float4 v = src4[tid + t * 1024];
                const int base = (tid + t * 1024) * 4;
                float f[4] = {v.x, v.y, v.z, v.w};
                #pragma unroll
                for (int e = 0; e < 4; ++e) {
                    uint32_t uk = fkey(f[e]);
                    if (uk > kthr) {
                        uint32_t pos = atomicAdd(&lcnt, 1u);
                        if (pos < CAP2)
                            s[pos] = ((unsigned long long)uk << 16) |
                                     (unsigned long long)(65535 - (base + e));
                    }
                }
            }
            __syncthreads();
            const uint32_t cc = lcnt;
            if (cc >= TOPK && cc <= CAP2) break;
            if (tid == 0) {
                if (cc < TOPK) { s_khi = s_kthr; s_kthr = s_klo + ((s_kthr - s_klo) >> 1); }
                else           { s_klo = s_kthr; s_kthr = s_kthr + ((s_khi - s_kthr) >> 1); }
            }
            __syncthreads();
        }
        c = min(lcnt, (uint32_t)CAP2);
        __syncthreads();
    }

    int M = 128;
    while (M < (int)c) M <<= 1;
    for (int i = tid; i < M; i += 1024) if (i >= (int)c) s[i] = 0ull;
    __syncthreads();
    for (int len = 2; len <= M; len <<= 1) {
        for (int inc = len >> 1; inc > 0; inc >>= 1) {
            for (int i = tid; i < M; i += 1024) {
                int j = i ^ inc;
                if (j > i) {
                    bool desc = ((i & len) == 0);
                    unsigned long long a = s[i], d = s[j];
                    if ((a < d) == desc) { s[i] = d; s[j] = a; }
                }
            }
            __syncthreads();
        }
    }
    const int obase = which * 6400 + b * TOPK;
    for (int j = tid; j < TOPK; j += 1024) {
        unsigned long long key = s[j];
        uint32_t idx = 65535u - (uint32_t)(key & 0xFFFFull);
        xy[obase + j]         = (float)(idx & (WIMG - 1));
        xy[12800 + obase + j] = (float)(idx >> 8);
    }
}

__global__ __launch_bounds__(128) void loss_final_kernel(
    const float* __restrict__ ab_p,  const float* __restrict__ ang_p,
    const float* __restrict__ ab_t,  const float* __restrict__ ang_t,
    const int*   __restrict__ ind,   const int*   __restrict__ reg_mask,
    const float* __restrict__ xy,    float* __restrict__ partials,
    uint32_t* __restrict__ done_cnt, float* __restrict__ out)
{
    const int b = blockIdx.x;
    const int j = threadIdx.x;
    float loss = 0.f, msum = 0.f;
    if (j < TOPK) {
        const int i = b * TOPK + j;
        float m = (float)reg_mask[i];
        msum = m;
        int id = ind[i];
        float xp = xy[i];
        float xt = xy[6400 + i];
        float yp = xy[12800 + i];
        float yt = xy[19200 + i];
        float ab0 = ab_p[(size_t)(b * 2 + 0) * HW + id];
        float ab1 = ab_p[(size_t)(b * 2 + 1) * HW + id];
        float ang = ang_p[(size_t)b * HW + id];
        float px = xp * m, py = yp * m;
        float pw = 2.f * ab0 * m, ph = 2.f * ab1 * m;
        float pr = (ang - 90.f) * m;
        float tx = xt * m, ty = yt * m;
        float tw = 2.f * ab_t[b * 200 + j * 2 + 0] * m;
        float th = 2.f * ab_t[b * 200 + j * 2 + 1] * m;
        float trg = (ang_t[i] - 90.f) * m;
        loss = gwd(px, py, pw, ph, pr, tx, ty, tw, th, trg);
    }
    #pragma unroll
    for (int off = 32; off > 0; off >>= 1) {
        loss += __shfl_down(loss, off);
        msum += __shfl_down(msum, off);
    }
    __shared__ float sl[2], sm[2];
    __shared__ uint32_t s_old;
    if ((threadIdx.x & 63) == 0) { sl[threadIdx.x >> 6] = loss; sm[threadIdx.x >> 6] = msum; }
    __syncthreads();
    if (threadIdx.x == 0) {
        __hip_atomic_store(&partials[b * 2],     sl[0] + sl[1], __ATOMIC_RELEASE, AGENT);
        __hip_atomic_store(&partials[b * 2 + 1], sm[0] + sm[1], __ATOMIC_RELEASE, AGENT);
        s_old = __hip_atomic_fetch_add(done_cnt, 1u, __ATOMIC_ACQ_REL, AGENT);
    }
    __syncthreads();
    if (s_old == 63u && threadIdx.x < 64) {
        float L = __hip_atomic_load(&partials[2 * threadIdx.x],     __ATOMIC_ACQUIRE, AGENT);
        float M = __hip_atomic_load(&partials[2 * threadIdx.x + 1], __ATOMIC_ACQUIRE, AGENT);
        #pragma unroll
        for (int off = 32; off > 0; off >>= 1) {
            L += __shfl_down(L, off);
            M += __shfl_down(M, off);
        }
        if (threadIdx.x == 0) out[0] = L / (M + 1e-8f);
    }
}

extern "C" void kernel_launch(void* const* d_in, const int* in_sizes, int n_in,
                              void* d_out, int out_size, void* d_ws, size_t ws_size,
                              hipStream_t stream)
{
    const float* hm_p  = (const float*)d_in[0];
    const float* ab_p  = (const float*)d_in[1];
    const float* ang_p = (const float*)d_in[2];
    const float* hm_t  = (const float*)d_in[3];
    const float* ab_t  = (const float*)d_in[4];
    const float* ang_t = (const float*)d_in[5];
    const int*   ind      = (const int*)d_in[6];
    const int*   reg_mask = (const int*)d_in[7];
    float* out = (float*)d_out;

    if (ws_size >= WS_FAST_BYTES) {
        unsigned long long* cand = (unsigned long long*)((char*)d_ws + CAND_OFF);
        uint32_t* cnt   = (uint32_t*)((char*)d_ws + CNT_OFF);
        float*    part  = (float*)((char*)d_ws + PART_OFF);
        uint32_t* done  = (uint32_t*)((char*)d_ws + DONE_OFF);

        filter_kernel<<<NGROUP * NCHUNK, FTHR, 0, stream>>>(hm_p, hm_t, cand, cnt, done);
        rank_loss_kernel<<<64, 256, 0, stream>>>(
            hm_p, hm_t, ab_p, ang_p, ab_t, ang_t, ind, reg_mask,
            cand, cnt, part, done, out);
    } else {
        float*    xy    = (float*)((char*)d_ws + XY_OFF2);
        float*    part  = (float*)((char*)d_ws + PART_OFF2);
        uint32_t* fdone = (uint32_t*)((char*)d_ws + FDONE_OFF2);
        topk_sort_kernel<<<NGROUP, 1024, 0, stream>>>(hm_p, hm_t, xy, fdone);
        loss_final_kernel<<<64, 128, 0, stream>>>(ab_p, ang_p, ab_t, ang_t, ind,
                                                  reg_mask, xy, part, fdone, out);
    }
}

// Round 13
// 21.335 us; speedup vs baseline: 1.0506x; 1.0506x over previous
//
#include <hip/hip_runtime.h>
#include <stdint.h>

#define HW 65536
#define WIMG 256
#define TOPK 100
#define CAP2 2048            // LDS candidate capacity (fallback path)
#define CAPC 64              // per-(group,chunk) slab capacity (E=20.5, 9.6 sigma)
#define NCHUNK 8             // filter blocks per group
#define NGROUP 128           // 64 batches x 2 heatmaps
#define FTHR 512             // filter block size (1024 blocks x 8 waves = full machine)

// Monotone float->uint key (handles negatives; data is [0,1)).
__device__ __forceinline__ uint32_t fkey(float v) {
    uint32_t b = __float_as_uint(v);
    return b ^ ((b & 0x80000000u) ? 0xFFFFFFFFu : 0x80000000u);
}

// ws byte layout (fast path):
//   [0, 524288)         u64 cand[1024][64]
//   [524288, 528384)    u32 chunkcnt[1024]
//   [528384, 630784)    f32 xy[25600]  (xs_p | xs_t | ys_p | ys_t, each 64*100)
//   [630784, 631296)    f32 partials[128]  (loss,mask per batch)
//   [631296, 631300)    u32 done counter
#define CAND_OFF  0
#define CNT_OFF   524288
#define XY_OFF    528384
#define PART_OFF  630784
#define DONE_OFF  631296
#define WS_FAST_BYTES 631300

// top-100 of 65536 uniforms ~ 0.99847; 0.9975 gives E=164/group, E=20.5/chunk
// (bisection fallback in sort_emit preserves correctness for arbitrary data)
#define FILT_THR 0.9975f

#define AGENT __HIP_MEMORY_SCOPE_AGENT

// ---------------- kernel A: filter (1024 blocks x 512 thr) ----------------
__global__ __launch_bounds__(FTHR) void filter_kernel(
    const float* __restrict__ hm_p, const float* __restrict__ hm_t,
    unsigned long long* __restrict__ cand, uint32_t* __restrict__ chunkcnt)
{
    __shared__ unsigned long long lbuf[CAPC];
    __shared__ uint32_t lcnt;

    const int blk   = blockIdx.x;        // 0..1023
    const int group = blk >> 3;
    const int chunk = blk & (NCHUNK - 1);
    const int which = group & 1;
    const int b     = group >> 1;
    const float* src = (which ? hm_t : hm_p) + (size_t)b * HW + chunk * (HW / NCHUNK);
    const float4* src4 = (const float4*)src;
    const int base0 = chunk * (HW / NCHUNK);

    if (threadIdx.x == 0) lcnt = 0;
    __syncthreads();

    #pragma unroll
    for (int t = 0; t < HW / NCHUNK / 4 / FTHR; ++t) {   // 4 iters
        const int i = threadIdx.x + t * FTHR;
        float4 v = src4[i];
        const int base = base0 + i * 4;
        float f[4] = {v.x, v.y, v.z, v.w};
        #pragma unroll
        for (int e = 0; e < 4; ++e) {
            if (f[e] > FILT_THR) {                      // float cmp; key only on hit
                uint32_t pos = atomicAdd(&lcnt, 1u);    // LDS atomic: intra-CU
                if (pos < CAPC)
                    lbuf[pos] = ((unsigned long long)fkey(f[e]) << 16) |
                                (unsigned long long)(65535 - (base + e));
            }
        }
    }
    __syncthreads();
    const uint32_t c = lcnt;
    if (threadIdx.x == 0) chunkcnt[blk] = c;            // plain store
    unsigned long long* gc = cand + (size_t)blk * CAPC;
    if (threadIdx.x < min(c, (uint32_t)CAPC))
        gc[threadIdx.x] = lbuf[threadIdx.x];            // c <= 64 < 512
}

// ------- kernel B: gather + rank-select + emit xy (128 blocks, 2 barriers) --
__global__ __launch_bounds__(256) void sort_emit_kernel(
    const float* __restrict__ hm_p, const float* __restrict__ hm_t,
    const unsigned long long* __restrict__ cand, const uint32_t* __restrict__ chunkcnt,
    float* __restrict__ xy, uint32_t* __restrict__ done_cnt)
{
    __shared__ unsigned long long s[CAP2];
    __shared__ uint32_t s_cs[NCHUNK], s_off[NCHUNK];
    __shared__ uint32_t s_meta[2];          // [0]=total/c, [1]=ok flag
    __shared__ uint32_t s_cnt, s_kthr, s_klo, s_khi;

    const int tid   = threadIdx.x;
    const int group = blockIdx.x;
    const int which = group & 1;
    const int b     = group >> 1;

    if (group == 0 && tid == 0) *done_cnt = 0;   // reset for loss kernel (stream-ordered)

    if (tid < NCHUNK) s_cs[tid] = chunkcnt[group * NCHUNK + tid];
    __syncthreads();
    if (tid == 0) {
        uint32_t off = 0; int ok = 1;
        #pragma unroll
        for (int k = 0; k < NCHUNK; ++k) {
            s_off[k] = off;
            if (s_cs[k] > CAPC) ok = 0;
            off += s_cs[k];
        }
        s_meta[0] = off;
        s_meta[1] = (ok && off >= TOPK && off <= CAP2) ? 1u : 0u;
    }
    __syncthreads();

    uint32_t c;
    if (s_meta[1]) {
        // parallel gather: 8 slabs x 32 lanes
        const int k  = tid >> 5;
        const int i0 = tid & 31;
        const unsigned long long* gc = cand + (size_t)(group * NCHUNK + k) * CAPC;
        const uint32_t ck = s_cs[k], ofk = s_off[k];
        for (uint32_t i = i0; i < ck; i += 32) s[ofk + i] = gc[i];
        c = s_meta[0];
    } else {
        // ---- fallback: full bisection scan (pathological data only) ----
        const float* src = (which ? hm_t : hm_p) + (size_t)b * HW;
        const float4* src4 = (const float4*)src;
        if (tid == 0) { s_kthr = fkey(0.99f); s_klo = 0u; s_khi = 0xFFFFFFFFu; }
        __syncthreads();
        for (int it = 0; it < 48; ++it) {
            if (tid == 0) s_cnt = 0;
            __syncthreads();
            const uint32_t kthr = s_kthr;
            for (int t = 0; t < HW / 4 / 256; ++t) {
                float4 v = src4[tid + t * 256];
                const int base = (tid + t * 256) * 4;
                float f[4] = {v.x, v.y, v.z, v.w};
                #pragma unroll
                for (int e = 0; e < 4; ++e) {
                    uint32_t uk = fkey(f[e]);
                    if (uk > kthr) {
                        uint32_t pos = atomicAdd(&s_cnt, 1u);
                        if (pos < CAP2)
                            s[pos] = ((unsigned long long)uk << 16) |
                                     (unsigned long long)(65535 - (base + e));
                    }
                }
            }
            __syncthreads();
            const uint32_t cc = s_cnt;
            if (cc >= TOPK && cc <= CAP2) break;
            if (tid == 0) {
                if (cc < TOPK) { s_khi = s_kthr; s_kthr = s_klo + ((s_kthr - s_klo) >> 1); }
                else           { s_klo = s_kthr; s_kthr = s_kthr + ((s_khi - s_kthr) >> 1); }
            }
            __syncthreads();
        }
        c = min(s_cnt, (uint32_t)CAP2);
    }
    __syncthreads();                         // s[0..c) visible to all

    const int obase = which * 6400 + b * TOPK;

    if (c < TOPK) {                          // rare: pad like bitonic's zero-keys
        for (int j = tid; j < TOPK; j += 256) {
            xy[obase + j]         = 255.f;
            xy[12800 + obase + j] = 255.f;
        }
        __syncthreads();                     // order pad stores before rank stores
    }

    // rank selection: unique composite keys -> unique ranks; broadcast LDS reads
    for (int i = tid; i < (int)c; i += 256) {
        const unsigned long long mine = s[i];
        int rank = 0;
        for (int j = 0; j < (int)c; ++j)
            rank += (s[j] > mine) ? 1 : 0;
        if (rank < TOPK) {
            uint32_t idx = 65535u - (uint32_t)(mine & 0xFFFFull);
            xy[obase + rank]         = (float)(idx & (WIMG - 1));  // x
            xy[12800 + obase + rank] = (float)(idx >> 8);          // y
        }
    }
}

// ---------------- loss ----------------
__device__ __forceinline__ float gwd(float px, float py, float pw, float ph, float pr,
                                     float tx, float ty, float tw, float th, float trg)
{
    pw = fminf(fmaxf(pw, 1e-7f), 1e7f);  ph = fminf(fmaxf(ph, 1e-7f), 1e7f);
    tw = fminf(fmaxf(tw, 1e-7f), 1e7f);  th = fminf(fmaxf(th, 1e-7f), 1e7f);
    const float d2r = 0.017453292519943295f;
    float rp = pr * d2r, rt = trg * d2r;
    float cp = cosf(rp), sp = sinf(rp);
    float ct = cosf(rt), st = sinf(rt);
    float ap = 0.5f * pw, bp = 0.5f * ph;
    float at = 0.5f * tw, bt = 0.5f * th;
    float ap2 = ap * ap, bp2 = bp * bp, at2 = at * at, bt2 = bt * bt;
    float p00 = ap2 * cp * cp + bp2 * sp * sp;
    float p11 = ap2 * sp * sp + bp2 * cp * cp;
    float p01 = (ap2 - bp2) * cp * sp;
    float t00 = at2 * ct * ct + bt2 * st * st;
    float t11 = at2 * st * st + bt2 * ct * ct;
    float t01 = (at2 - bt2) * ct * st;
    float dx = px - tx, dy = py - ty;
    float xyd = dx * dx + dy * dy;
    float whr = ap2 + bp2 + at2 + bt2;
    float trc = p00 * t00 + 2.f * p01 * t01 + p11 * t11;
    float dets = (ap * bp) * (at * bt);
    whr -= 2.f * sqrtf(fmaxf(trc + 2.f * dets, 0.f));
    float dist = fmaxf(xyd + whr, 0.f);
    float d = log1pf(dist);
    return 1.f - 1.f / (1.f + d);
}

// 64 blocks (one per batch) + device-scope last-block finalize (R5-proven).
__global__ __launch_bounds__(128) void loss_final_kernel(
    const float* __restrict__ ab_p,  const float* __restrict__ ang_p,
    const float* __restrict__ ab_t,  const float* __restrict__ ang_t,
    const int*   __restrict__ ind,   const int*   __restrict__ reg_mask,
    const float* __restrict__ xy,    float* __restrict__ partials,
    uint32_t* __restrict__ done_cnt, float* __restrict__ out)
{
    const int b = blockIdx.x;
    const int j = threadIdx.x;
    float loss = 0.f, msum = 0.f;
    if (j < TOPK) {
        const int i = b * TOPK + j;
        float m = (float)reg_mask[i];
        msum = m;
        int id = ind[i];
        float xp = xy[i];
        float xt = xy[6400 + i];
        float yp = xy[12800 + i];
        float yt = xy[19200 + i];
        float ab0 = ab_p[(size_t)(b * 2 + 0) * HW + id];
        float ab1 = ab_p[(size_t)(b * 2 + 1) * HW + id];
        float ang = ang_p[(size_t)b * HW + id];
        float px = xp * m, py = yp * m;
        float pw = 2.f * ab0 * m, ph = 2.f * ab1 * m;
        float pr = (ang - 90.f) * m;
        float tx = xt * m, ty = yt * m;
        float tw = 2.f * ab_t[b * 200 + j * 2 + 0] * m;
        float th = 2.f * ab_t[b * 200 + j * 2 + 1] * m;
        float trg = (ang_t[i] - 90.f) * m;
        loss = gwd(px, py, pw, ph, pr, tx, ty, tw, th, trg);
    }
    #pragma unroll
    for (int off = 32; off > 0; off >>= 1) {
        loss += __shfl_down(loss, off);
        msum += __shfl_down(msum, off);
    }
    __shared__ float sl[2], sm[2];
    __shared__ uint32_t s_old;
    if ((threadIdx.x & 63) == 0) { sl[threadIdx.x >> 6] = loss; sm[threadIdx.x >> 6] = msum; }
    __syncthreads();
    if (threadIdx.x == 0) {
        __hip_atomic_store(&partials[b * 2],     sl[0] + sl[1], __ATOMIC_RELEASE, AGENT);
        __hip_atomic_store(&partials[b * 2 + 1], sm[0] + sm[1], __ATOMIC_RELEASE, AGENT);
        s_old = __hip_atomic_fetch_add(done_cnt, 1u, __ATOMIC_ACQ_REL, AGENT);
    }
    __syncthreads();
    if (s_old == 63u && threadIdx.x < 64) {
        float L = __hip_atomic_load(&partials[2 * threadIdx.x],     __ATOMIC_ACQUIRE, AGENT);
        float M = __hip_atomic_load(&partials[2 * threadIdx.x + 1], __ATOMIC_ACQUIRE, AGENT);
        #pragma unroll
        for (int off = 32; off > 0; off >>= 1) {
            L += __shfl_down(L, off);
            M += __shfl_down(M, off);
        }
        if (threadIdx.x == 0) out[0] = L / (M + 1e-8f);
    }
}

// ---------------- slow path (tiny ws): R8 structure, unchanged ----------------
#define XY_OFF2    0
#define PART_OFF2  102400
#define FDONE_OFF2 102912

__global__ __launch_bounds__(1024) void topk_sort_kernel(
    const float* __restrict__ hm_p, const float* __restrict__ hm_t,
    float* __restrict__ xy, uint32_t* __restrict__ fdone)
{
    __shared__ unsigned long long s[CAP2];
    __shared__ uint32_t lcnt, s_kthr, s_klo, s_khi;

    const int tid   = threadIdx.x;
    const int group = blockIdx.x;
    const int which = group & 1;
    const int b     = group >> 1;

    if (group == 0 && tid == 0) *fdone = 0u;

    const float* src = (which ? hm_t : hm_p) + (size_t)b * HW;
    const float4* src4 = (const float4*)src;

    if (tid == 0) lcnt = 0;
    __syncthreads();
    #pragma unroll 4
    for (int t = 0; t < HW / 4 / 1024; ++t) {
        const int i = tid + t * 1024;
        float4 v = src4[i];
        const int base = i * 4;
        float f[4] = {v.x, v.y, v.z, v.w};
        #pragma unroll
        for (int e = 0; e < 4; ++e) {
            if (f[e] > FILT_THR) {
                uint32_t pos = atomicAdd(&lcnt, 1u);
                if (pos < CAP2)
                    s[pos] = ((unsigned long long)fkey(f[e]) << 16) |
                             (unsigned long long)(65535 - (base + e));
            }
        }
    }
    __syncthreads();
    uint32_t c = lcnt;

    if (c < TOPK || c > CAP2) {
        if (tid == 0) { s_kthr = fkey(0.99f); s_klo = 0u; s_khi = 0xFFFFFFFFu; }
        __syncthreads();
        for (int it = 0; it < 48; ++it) {
            if (tid == 0) lcnt = 0;
            __syncthreads();
            const uint32_t kthr = s_kthr;
            for (int t = 0; t < HW / 4 / 1024; ++t) {
                float4 v = src4[tid + t * 1024];
                const int base = (tid + t * 1024) * 4;
                float f[4] = {v.x, v.y, v.z, v.w};
                #pragma unroll
                for (int e = 0; e < 4; ++e) {
                    uint32_t uk = fkey(f[e]);
                    if (uk > kthr) {
                        uint32_t pos = atomicAdd(&lcnt, 1u);
                        if (pos < CAP2)
                            s[pos] = ((unsigned long long)uk << 16) |
                                     (unsigned long long)(65535 - (base + e));
                    }
                }
            }
            __syncthreads();
            const uint32_t cc = lcnt;
            if (cc >= TOPK && cc <= CAP2) break;
            if (tid == 0) {
                if (cc < TOPK) { s_khi = s_kthr; s_kthr = s_klo + ((s_kthr - s_klo) >> 1); }
                else           { s_klo = s_kthr; s_kthr = s_kthr + ((s_khi - s_kthr) >> 1); }
            }
            __syncthreads();
        }
        c = min(lcnt, (uint32_t)CAP2);
        __syncthreads();
    }

    int M = 128;
    while (M < (int)c) M <<= 1;
    for (int i = tid; i < M; i += 1024) if (i >= (int)c) s[i] = 0ull;
    __syncthreads();
    for (int len = 2; len <= M; len <<= 1) {
        for (int inc = len >> 1; inc > 0; inc >>= 1) {
            for (int i = tid; i < M; i += 1024) {
                int j = i ^ inc;
                if (j > i) {
                    bool desc = ((i & len) == 0);
                    unsigned long long a = s[i], d = s[j];
                    if ((a < d) == desc) { s[i] = d; s[j] = a; }
                }
            }
            __syncthreads();
        }
    }
    const int obase = which * 6400 + b * TOPK;
    for (int j = tid; j < TOPK; j += 1024) {
        unsigned long long key = s[j];
        uint32_t idx = 65535u - (uint32_t)(key & 0xFFFFull);
        xy[obase + j]         = (float)(idx & (WIMG - 1));
        xy[12800 + obase + j] = (float)(idx >> 8);
    }
}

extern "C" void kernel_launch(void* const* d_in, const int* in_sizes, int n_in,
                              void* d_out, int out_size, void* d_ws, size_t ws_size,
                              hipStream_t stream)
{
    const float* hm_p  = (const float*)d_in[0];
    const float* ab_p  = (const float*)d_in[1];
    const float* ang_p = (const float*)d_in[2];
    const float* hm_t  = (const float*)d_in[3];
    const float* ab_t  = (const float*)d_in[4];
    const float* ang_t = (const float*)d_in[5];
    const int*   ind      = (const int*)d_in[6];
    const int*   reg_mask = (const int*)d_in[7];
    float* out = (float*)d_out;

    if (ws_size >= WS_FAST_BYTES) {
        unsigned long long* cand = (unsigned long long*)((char*)d_ws + CAND_OFF);
        uint32_t* cnt   = (uint32_t*)((char*)d_ws + CNT_OFF);
        float*    xy    = (float*)((char*)d_ws + XY_OFF);
        float*    part  = (float*)((char*)d_ws + PART_OFF);
        uint32_t* done  = (uint32_t*)((char*)d_ws + DONE_OFF);

        filter_kernel<<<NGROUP * NCHUNK, FTHR, 0, stream>>>(hm_p, hm_t, cand, cnt);
        sort_emit_kernel<<<NGROUP, 256, 0, stream>>>(hm_p, hm_t, cand, cnt, xy, done);
        loss_final_kernel<<<64, 128, 0, stream>>>(ab_p, ang_p, ab_t, ang_t, ind,
                                                  reg_mask, xy, part, done, out);
    } else {
        float*    xy    = (float*)((char*)d_ws + XY_OFF2);
        float*    part  = (float*)((char*)d_ws + PART_OFF2);
        uint32_t* fdone = (uint32_t*)((char*)d_ws + FDONE_OFF2);
        topk_sort_kernel<<<NGROUP, 1024, 0, stream>>>(hm_p, hm_t, xy, fdone);
        loss_final_kernel<<<64, 128, 0, stream>>>(ab_p, ang_p, ab_t, ang_t, ind,
                                                  reg_mask, xy, part, fdone, out);
    }
}